// Round 4
// baseline (562.600 us; speedup 1.0000x reference)
//
#include <hip/hip_runtime.h>

// BidirectionalBoxPool, MI355X. float32 in/out.
// feats (N,K,2,C,PH,MW) ++ widths (N,K,2), MW derived from out_size.
// d=1 is an exact flip of d=0 (wf==width>=8 for valid boxes): compute each
// bilinear sample once, store to both directions.
// Activity-packed: only active column-pairs run the gather channel-loop
// (freed lanes redistributed over channel groups); dead columns zero-filled
// with aligned float4 stores. R4 fix: guard the odd-MW straggler (j==MW)
// which previously stored out of row bounds for the max-width box.

namespace {
constexpr int kN = 8, kK = 64, kC = 128, kH = 128, kW = 128, kPH = 8;
constexpr int kHW = kH * kW;

__global__ __launch_bounds__(256) void boxpool_kernel(
    const float* __restrict__ x,
    const float* __restrict__ boxes,
    float* __restrict__ out,
    const int MW)
{
  const int b = blockIdx.x;          // (n*kK + k)*2 + chalf
  const int nk = b >> 1;
  const int chalf = b & 1;
  const int n = nk >> 6;             // kK == 64
  const int tid = threadIdx.x;

  // ---- box setup (block-uniform) ----
  const int bb = nk * 4;
  const float xmin = boxes[bb + 0];
  const float ymin = boxes[bb + 1];
  const float xmax = boxes[bb + 2];
  const float ymax = boxes[bb + 3];
  const bool valid = !(xmin == 0.f && ymin == 0.f && xmax == 0.f && ymax == 0.f);
  const float bw = valid ? (xmax - xmin) : 1.f;
  const float bh = valid ? (ymax - ymin) : 1.f;
  const bool wide = bw > bh;
  const float ratio = wide ? (bw / bh) : (bh / bw);
  const int width = valid ? (int)ceilf(ratio * 8.f) : 0;  // bit-matches np fp32
  const float wf = fmaxf((float)width, 2.f);
  const int wm = width < MW ? width : MW;

  const int points = kPH * MW;
  const size_t feats_sz = (size_t)kN * kK * 2 * kC * points;

  if (chalf == 0 && tid == 0) {
    out[feats_sz + (size_t)nk * 2 + 0] = (float)width;
    out[feats_sz + (size_t)nk * 2 + 1] = (float)width;
  }

  const float* __restrict__ xn = x + ((size_t)n * kC + (size_t)chalf * 64) * kHW;
  float* __restrict__ out0 = out + ((size_t)(nk * 2 + 0) * kC + (size_t)chalf * 64) * points;
  float* __restrict__ out1 = out + ((size_t)(nk * 2 + 1) * kC + (size_t)chalf * 64) * points;

  // ================= active phase =================
  const int cp2 = (wm + 1) >> 1;      // active col-pairs per row
  const int Pact = kPH * cp2;         // total active pair-slots
  const bool mwEven = (MW & 1) == 0;

  if (Pact > 0) {
    int Pp, cpl;                      // pair-slots, channels per lane
    if (Pact <= 64)       { Pp = 64;  cpl = 16; }
    else if (Pact <= 128) { Pp = 128; cpl = 32; }
    else                  { Pp = 256; cpl = 64; }
    const int pid0 = tid % Pp;
    const int c0   = (tid / Pp) * cpl;

    for (int pid = pid0; pid < Pact; pid += Pp) {
      const int i   = pid / cp2;
      const int ja2 = pid - i * cp2;
      const int j0  = 2 * ja2;
      const bool hasS1 = (j0 + 1 < MW);   // straggler guard (odd MW, wm==MW)

      int   off[8];
      float wgt[8];
      int   e1[2];

#pragma unroll
      for (int s = 0; s < 2; ++s) {
        const int j = j0 + s;
        const bool inRow = (s == 0) || hasS1;
        // d=1 flip: valid cols reverse; dead col (odd-wm straggler) stays put
        const int jc = inRow ? j : 0;                 // safe placeholder
        const int jp = (jc < wm) ? (wm - 1 - jc) : jc;
        e1[s] = (kPH - 1 - i) * MW + jp;

        float w00 = 0.f, w10 = 0.f, w01 = 0.f, w11 = 0.f;
        int   o00 = 0, o10 = 0, o01 = 0, o11 = 0;
        if (inRow && j < wm) {
          const float jf = (float)j, iff = (float)i;
          float gx, gy;
          if (wide) {
            gx = (xmin + (jf * bw) / (wf - 1.f) - 64.f) / 64.f;
            gy = (ymin + (iff * bh) / 7.f - 64.f) / 64.f;
          } else {
            gx = (xmin + (iff * bw) / 7.f - 64.f) / 64.f;
            gy = (ymin + ((wf - jf) * bh) / (wf - 1.f) - 64.f) / 64.f;
          }
          const float ix = ((gx + 1.f) * 128.f - 1.f) * 0.5f;
          const float iy = ((gy + 1.f) * 128.f - 1.f) * 0.5f;
          const float x0 = floorf(ix), y0 = floorf(iy);
          const float wx1 = ix - x0, wx0 = (x0 + 1.f) - ix;
          const float wy1 = iy - y0, wy0 = (y0 + 1.f) - iy;
          const int xi = (int)x0, yi = (int)y0;
          const bool xb0 = (xi >= 0) && (xi <= kW - 1);
          const bool xb1 = (xi + 1 >= 0) && (xi + 1 <= kW - 1);
          const bool yb0 = (yi >= 0) && (yi <= kH - 1);
          const bool yb1 = (yi + 1 >= 0) && (yi + 1 <= kH - 1);
          const int x0c = min(max(xi, 0), kW - 1);
          const int x1c = min(max(xi + 1, 0), kW - 1);
          const int y0c = min(max(yi, 0), kH - 1);
          const int y1c = min(max(yi + 1, 0), kH - 1);
          o00 = y0c * kW + x0c; o10 = y0c * kW + x1c;
          o01 = y1c * kW + x0c; o11 = y1c * kW + x1c;
          w00 = (xb0 && yb0) ? wx0 * wy0 : 0.f;
          w10 = (xb1 && yb0) ? wx1 * wy0 : 0.f;
          w01 = (xb0 && yb1) ? wx0 * wy1 : 0.f;
          w11 = (xb1 && yb1) ? wx1 * wy1 : 0.f;
        }
        off[4 * s + 0] = o00; off[4 * s + 1] = o10;
        off[4 * s + 2] = o01; off[4 * s + 3] = o11;
        wgt[4 * s + 0] = w00; wgt[4 * s + 1] = w10;
        wgt[4 * s + 2] = w01; wgt[4 * s + 3] = w11;
      }

      const int base0 = i * MW + j0;
      const int cend = c0 + cpl;
#pragma unroll 4
      for (int c = c0; c < cend; ++c) {
        const float* __restrict__ plc = xn + (size_t)c * kHW;  // uniform base
        const float vA = wgt[0] * plc[off[0]] + wgt[1] * plc[off[1]]
                       + wgt[2] * plc[off[2]] + wgt[3] * plc[off[3]];
        const float vB = wgt[4] * plc[off[4]] + wgt[5] * plc[off[5]]
                       + wgt[6] * plc[off[6]] + wgt[7] * plc[off[7]];
        float* o0c = out0 + (size_t)c * points;
        float* o1c = out1 + (size_t)c * points;
        if (hasS1) {
          if (mwEven) {                    // base0 even -> 8B aligned
            float2 v2; v2.x = vA; v2.y = vB;
            *reinterpret_cast<float2*>(o0c + base0) = v2;
          } else {
            o0c[base0] = vA;
            o0c[base0 + 1] = vB;
          }
          o1c[e1[0]] = vA;
          o1c[e1[1]] = vB;
        } else {                           // straggler pair: single element
          o0c[base0] = vA;
          o1c[e1[0]] = vA;
        }
      }
    }
  }

  // ================= dead-column zero-fill =================
  const int ja0 = 2 * cp2;            // first always-dead column
  const int dl  = MW - ja0;
  if (dl > 0) {
    // 1024 runs: (dir, c, i); each run is dl contiguous floats
    for (int r = tid; r < 2 * 64 * kPH; r += 256) {
      const int dir = r & 1;
      const int c   = (r >> 1) & 63;
      const int i   = r >> 7;
      float* base = (dir ? out1 : out0) + (size_t)c * points + i * MW + ja0;
      int t = 0;
      int head = (int)((4 - ((((uintptr_t)base) >> 2) & 3)) & 3);
      head = head < dl ? head : dl;
      for (; t < head; ++t) base[t] = 0.f;
      for (; t + 4 <= dl; t += 4) {
        float4 z; z.x = 0.f; z.y = 0.f; z.z = 0.f; z.w = 0.f;
        *reinterpret_cast<float4*>(base + t) = z;
      }
      for (; t < dl; ++t) base[t] = 0.f;
    }
  }
}
}  // namespace

extern "C" void kernel_launch(void* const* d_in, const int* in_sizes, int n_in,
                              void* d_out, int out_size, void* d_ws, size_t ws_size,
                              hipStream_t stream) {
  (void)in_sizes; (void)n_in; (void)d_ws; (void)ws_size;
  const float* x = (const float*)d_in[0];
  const float* boxes = (const float*)d_in[1];
  float* out = (float*)d_out;

  // out_size = N*K*2*C*PH*MW + N*K*2  ->  MW
  const long long widths_elems = (long long)kN * kK * 2;            // 1024
  const long long per_mw = (long long)kN * kK * 2 * kC * kPH;       // 1048576
  const int MW = (int)(((long long)out_size - widths_elems) / per_mw);

  boxpool_kernel<<<dim3(kN * kK * 2), dim3(256), 0, stream>>>(x, boxes, out, MW);
}